// Round 4
// baseline (292.627 us; speedup 1.0000x reference)
//
#include <hip/hip_runtime.h>
#include <math.h>

namespace {
constexpr int NB = 16, NP = 2048, KNN = 32, CH1 = 6, CH2 = 32;
constexpr int QPB = 16;                 // queries (waves) per knn block
constexpr int NBLK = NB * NP / QPB;     // 2048 knn blocks
constexpr float BN_EPS = 1e-5f;

// workspace byte offsets
constexpr size_t OFF_S1REP  = 0;       // double[8][12] replicated BN1 accum (768 B)
constexpr size_t OFF_STATS2 = 768;     // double[64] (sum[32], sumsq[32])
constexpr size_t OFF_SC1    = 1280;    // float[12]
constexpr size_t OFF_P      = 2048;                                 // float[NB*NP*6]
constexpr size_t OFF_MINQ   = OFF_P + sizeof(float)*NB*NP*CH1;      // float[NB*NP*6]
}

// ---------------- DPP wave-64 reductions (VALU pipe, no LDS) ----------------
template <int C> __device__ __forceinline__ int dpp0i(int x) {
  return __builtin_amdgcn_update_dpp(0, x, C, 0xf, 0xf, true);
}
template <int C> __device__ __forceinline__ float dpp0f(float x) {
  return __uint_as_float((unsigned)__builtin_amdgcn_update_dpp(
      0, (int)__float_as_uint(x), C, 0xf, 0xf, true));
}
template <int C> __device__ __forceinline__ float dppInff(float x) {
  return __uint_as_float((unsigned)__builtin_amdgcn_update_dpp(
      0x7F800000, (int)__float_as_uint(x), C, 0xf, 0xf, false));
}
__device__ __forceinline__ int wave_isum_bcast(int x) {
  x += dpp0i<0x111>(x); x += dpp0i<0x112>(x); x += dpp0i<0x114>(x);
  x += dpp0i<0x118>(x); x += dpp0i<0x142>(x); x += dpp0i<0x143>(x);
  return __builtin_amdgcn_readlane(x, 63);
}
__device__ __forceinline__ float wave_fsum63(float x) {
  x += dpp0f<0x111>(x); x += dpp0f<0x112>(x); x += dpp0f<0x114>(x);
  x += dpp0f<0x118>(x); x += dpp0f<0x142>(x); x += dpp0f<0x143>(x);
  return x;
}
__device__ __forceinline__ float wave_fmin63(float x) {
  x = fminf(x, dppInff<0x111>(x)); x = fminf(x, dppInff<0x112>(x));
  x = fminf(x, dppInff<0x114>(x)); x = fminf(x, dppInff<0x118>(x));
  x = fminf(x, dppInff<0x142>(x)); x = fminf(x, dppInff<0x143>(x));
  return x;
}

#define BSEL(m, x, y) ((((x)) & (m)) | (((y)) & ~(m)))  // -> v_bfi

// Fused: pq + KNN select + per-query min(q) + BN1 replicated-atomic partials.
// One WAVE per query; 16 waves/block share one staged batch tile.
__global__ __launch_bounds__(1024, 8) void knn_kernel(const float* __restrict__ x,
                                                      const float* __restrict__ W1,
                                                      const float* __restrict__ b1,
                                                      float* __restrict__ pout,
                                                      float* __restrict__ minq,
                                                      double* __restrict__ s1rep) {
  __shared__ float4 pts[NP];      // x,y,z,|x|^2 (32 KiB)
  __shared__ float red[12][QPB];
  const int lane = threadIdx.x & 63;
  const int w    = threadIdx.x >> 6;
  const int qi   = blockIdx.x * QPB + w;   // 16 | 2048 -> same batch per block
  const int b    = qi >> 11;
  const int n    = qi & (NP - 1);

  const float* xb = x + (size_t)b * NP * 3;
  for (int j = threadIdx.x; j < NP; j += 1024) {
    float a0 = xb[j*3+0], a1 = xb[j*3+1], a2 = xb[j*3+2];
    float sq = __fadd_rn(__fadd_rn(__fmul_rn(a0,a0), __fmul_rn(a1,a1)), __fmul_rn(a2,a2));
    pts[j] = make_float4(a0, a1, a2, sq);
  }
  __syncthreads();

  const float4 xq = pts[n];

  // distances, bit-exact vs reference formula. All d >= 0 for this data, so raw
  // float bits order correctly (sign plane unused by the select).
  unsigned a[32];
#pragma unroll
  for (int t = 0; t < 32; ++t) {
    float4 pj = pts[t*64 + lane];
    float dot = __fadd_rn(__fadd_rn(__fmul_rn(xq.x,pj.x), __fmul_rn(xq.y,pj.y)),
                          __fmul_rn(xq.z,pj.z));
    float d = __fsub_rn(__fadd_rn(xq.w, pj.w), __fmul_rn(2.0f, dot));
    a[31 - t] = __float_as_uint(d);
  }

  // 32x32 bit transpose, J=16 stage (full): after this the two 16-reg halves are
  // independent. Upper half -> planes of bits 31..16 (all we usually need).
#pragma unroll
  for (int g = 0; g < 16; ++g) {
    unsigned hi = a[g], lo = a[g+16];
    a[g]    = __builtin_amdgcn_perm(hi, lo, 0x07060302u);   // hi halves
    a[g+16] = __builtin_amdgcn_perm(hi, lo, 0x05040100u);   // lo halves
  }
  // upper half: J=8,4,2,1
#pragma unroll
  for (int g = 0; g < 8; ++g) {      // J=8, k in 0..7
    unsigned hi = a[g], lo = a[g+8];
    a[g]   = __builtin_amdgcn_perm(hi, lo, 0x07030501u);
    a[g+8] = __builtin_amdgcn_perm(hi, lo, 0x06020400u);
  }
#pragma unroll
  for (int g = 0; g < 8; ++g) {      // J=4
    int k = (g >> 2)*8 + (g & 3);
    unsigned A = a[k], B = a[k+4];
    a[k]   = BSEL(0x0F0F0F0Fu, B >> 4, A);
    a[k+4] = BSEL(0xF0F0F0F0u, A << 4, B);
  }
#pragma unroll
  for (int g = 0; g < 8; ++g) {      // J=2
    int k = (g >> 1)*4 + (g & 1);
    unsigned A = a[k], B = a[k+2];
    a[k]   = BSEL(0x33333333u, B >> 2, A);
    a[k+2] = BSEL(0xCCCCCCCCu, A << 2, B);
  }
#pragma unroll
  for (int g = 0; g < 8; ++g) {      // J=1
    int k = g*2;
    unsigned A = a[k], B = a[k+1];
    a[k]   = BSEL(0x55555555u, B >> 1, A);
    a[k+1] = BSEL(0xAAAAAAAAu, A << 1, B);
  }
  // a[i] (i=1..15) = plane of distance bit (31-i); bit v <-> candidate v*64+lane

  // radix select on bits 30..16, tracking alive-count in SALU
  unsigned alive = 0xFFFFFFFFu, below = 0u;
  int rem = KNN, ca = 2048;
#pragma unroll
  for (int i = 1; i <= 15; ++i) {
    unsigned zeros = alive & ~a[i];
    int c0 = wave_isum_bcast(__popc(zeros));
    if (c0 >= rem) { alive = zeros; ca = c0; }
    else { rem -= c0; below |= zeros; alive &= a[i]; ca -= c0; }
  }
  unsigned sel = below;
  if (ca == rem) {
    sel |= alive;
  } else {
    // rare path: finish the lower-half transpose (planes of bits 15..0) lazily
#pragma unroll
    for (int g = 0; g < 8; ++g) {    // J=8, k in 16..23
      unsigned hi = a[16+g], lo = a[24+g];
      a[16+g] = __builtin_amdgcn_perm(hi, lo, 0x07030501u);
      a[24+g] = __builtin_amdgcn_perm(hi, lo, 0x06020400u);
    }
#pragma unroll
    for (int g = 0; g < 8; ++g) {    // J=4
      int k = 16 + (g >> 2)*8 + (g & 3);
      unsigned A = a[k], B = a[k+4];
      a[k]   = BSEL(0x0F0F0F0Fu, B >> 4, A);
      a[k+4] = BSEL(0xF0F0F0F0u, A << 4, B);
    }
#pragma unroll
    for (int g = 0; g < 8; ++g) {    // J=2
      int k = 16 + (g >> 1)*4 + (g & 1);
      unsigned A = a[k], B = a[k+2];
      a[k]   = BSEL(0x33333333u, B >> 2, A);
      a[k+2] = BSEL(0xCCCCCCCCu, A << 2, B);
    }
#pragma unroll
    for (int g = 0; g < 8; ++g) {    // J=1
      int k = 16 + g*2;
      unsigned A = a[k], B = a[k+1];
      a[k]   = BSEL(0x55555555u, B >> 1, A);
      a[k+1] = BSEL(0xAAAAAAAAu, A << 1, B);
    }
#pragma unroll
    for (int i = 16; i < 32; ++i) {  // extend radix onto bits 15..0 while unresolved
      if (ca != rem) {
        unsigned zeros = alive & ~a[i];
        int c0 = wave_isum_bcast(__popc(zeros));
        if (c0 >= rem) { alive = zeros; ca = c0; }
        else { rem -= c0; below |= zeros; alive &= a[i]; ca -= c0; }
      }
    }
    sel = below;
    if (ca == rem) {
      sel |= alive;
    } else {
      // bit-identical distances: take smallest indices j = v*64+lane
      for (int v = 0; v < 32; ++v) {
        if (rem <= 0) break;
        bool mine = (alive >> v) & 1;
        unsigned long long mb = __ballot(mine);
        int c = __popcll(mb);
        if (c <= rem) { if (mine) sel |= 1u << v; rem -= c; }
        else {
          if (mine && (int)__popcll(mb & ((1ull << lane) - 1)) < rem) sel |= 1u << v;
          rem = 0;
        }
      }
    }
  }

  // gather: sum/sumsq/min of q_j over selected neighbors (q from LDS pts + SGPR W1)
  float w3[CH1], w4[CH1], w5[CH1];
#pragma unroll
  for (int c = 0; c < CH1; ++c) { w3[c]=W1[3*CH1+c]; w4[c]=W1[4*CH1+c]; w5[c]=W1[5*CH1+c]; }
  float sq_[CH1], sqq[CH1], mn[CH1];
#pragma unroll
  for (int c = 0; c < CH1; ++c) { sq_[c] = 0.f; sqq[c] = 0.f; mn[c] = INFINITY; }
  unsigned m = sel;
  while (m) {
    int v = __builtin_ctz(m); m &= m - 1;
    float4 pj = pts[(v << 6) | lane];
#pragma unroll
    for (int c = 0; c < CH1; ++c) {
      float qv = pj.x*w3[c] + pj.y*w4[c] + pj.z*w5[c];   // contraction OK here
      sq_[c] += qv; sqq[c] += qv*qv; mn[c] = fminf(mn[c], qv);
    }
  }

  // p_i for this query (uniform across lanes)
  float pv[CH1];
#pragma unroll
  for (int c = 0; c < CH1; ++c) {
    float qv = xq.x*w3[c] + xq.y*w4[c] + xq.z*w5[c];
    pv[c] = b1[c] + xq.x*W1[c] + xq.y*W1[CH1+c] + xq.z*W1[2*CH1+c] + qv;
  }

#pragma unroll
  for (int c = 0; c < CH1; ++c) {
    float s  = wave_fsum63(sq_[c]);
    float s2 = wave_fsum63(sqq[c]);
    float mm = wave_fmin63(mn[c]);
    if (lane == 63) {
      minq[qi*CH1 + c] = mm;
      red[c][w]       = fmaf(32.f, pv[c], -s);                            // sum_k (p-q)
      red[CH1 + c][w] = fmaf(32.f, pv[c]*pv[c], fmaf(-2.f*pv[c], s, s2)); // sum_k (p-q)^2
    }
  }
  if (lane == 0) {
#pragma unroll
    for (int c = 0; c < CH1; ++c) pout[qi*CH1 + c] = pv[c];
  }
  __syncthreads();
  if (threadIdx.x < 12) {
    float s = 0.f;
#pragma unroll
    for (int ww = 0; ww < QPB; ++ww) s += red[threadIdx.x][ww];
    atomicAdd(s1rep + (blockIdx.x & 7) * 12 + threadIdx.x, (double)s);
  }
}

// stage2: derive sc1 from replicated BN1 stats (block 0 publishes it), apply
// max_k ELU(affine(p - q_j)) == ELU(affine(p - min_k q_j)), accumulate BN2 stats.
__global__ __launch_bounds__(128) void stage2_kernel(const float* __restrict__ p,
                                                     const float* __restrict__ minq,
                                                     const double* __restrict__ s1rep,
                                                     const float* __restrict__ gamma1,
                                                     const float* __restrict__ beta1,
                                                     const float* __restrict__ W2,
                                                     const float* __restrict__ b2,
                                                     float* __restrict__ sc1g,
                                                     double* __restrict__ stats2) {
  __shared__ double tot1[12];
  __shared__ float sc1s[12];
  __shared__ float rs[2][CH2], rq[2][CH2];
  const int t = threadIdx.x;
  if (t < 12) {
    double s = 0.0;
#pragma unroll
    for (int r = 0; r < 8; ++r) s += s1rep[r*12 + t];
    tot1[t] = s;
  }
  __syncthreads();
  if (t < CH1) {
    double cnt  = (double)NB * NP * KNN;
    double mean = tot1[t] / cnt;
    double var  = tot1[CH1 + t] / cnt - mean * mean;
    float scale = gamma1[t] / sqrtf((float)var + BN_EPS);
    sc1s[t] = scale; sc1s[CH1 + t] = beta1[t] - (float)mean * scale;
  }
  __syncthreads();
  if (blockIdx.x == 0 && t < 12) sc1g[t] = sc1s[t];

  const int qi = blockIdx.x * 128 + t;
  const int w = t >> 6, lane = t & 63;
  float me[CH1];
#pragma unroll
  for (int c = 0; c < CH1; ++c) {
    float v = fmaf(sc1s[c], p[qi*CH1 + c] - minq[qi*CH1 + c], sc1s[CH1 + c]);
    me[c] = v > 0.f ? v : expm1f(v);
  }
#pragma unroll
  for (int o = 0; o < CH2; ++o) {
    float y = b2[o];
#pragma unroll
    for (int c = 0; c < CH1; ++c) y = fmaf(me[c], W2[c*CH2 + o], y);
    float s  = wave_fsum63(y);
    float s2 = wave_fsum63(y * y);
    if (lane == 63) { rs[w][o] = s; rq[w][o] = s2; }
  }
  __syncthreads();
  if (t < CH2) atomicAdd(stats2 + t, (double)(rs[0][t] + rs[1][t]));
  else if (t < 2*CH2) atomicAdd(stats2 + t, (double)(rq[0][t-CH2] + rq[1][t-CH2]));
}

// final: derive sc2 per block, recompute y, apply BN2 + ELU. 8 queries/block.
__global__ __launch_bounds__(256) void out_kernel(const float* __restrict__ p,
                                                  const float* __restrict__ minq,
                                                  const float* __restrict__ sc1,
                                                  const float* __restrict__ W2,
                                                  const float* __restrict__ b2,
                                                  const double* __restrict__ stats2,
                                                  const float* __restrict__ gamma2,
                                                  const float* __restrict__ beta2,
                                                  float* __restrict__ out) {
  __shared__ float me_lds[8][CH1];
  __shared__ float s2s[CH2], s2h[CH2];
  const int t = threadIdx.x;
  if (t < CH2) {
    double cnt  = (double)NB * NP;
    double mean = stats2[t] / cnt;
    double var  = stats2[CH2 + t] / cnt - mean * mean;
    float scale = gamma2[t] / sqrtf((float)var + BN_EPS);
    s2s[t] = scale; s2h[t] = beta2[t] - (float)mean * scale;
  }
  const int qbase = blockIdx.x * 8;
  if (t < 48) {
    int qs = t / 6, c = t % 6;
    int qi = qbase + qs;
    float v = fmaf(sc1[c], p[qi*CH1 + c] - minq[qi*CH1 + c], sc1[CH1 + c]);
    me_lds[qs][c] = v > 0.f ? v : expm1f(v);
  }
  __syncthreads();
  const int qs = t >> 5, o = t & 31;
  const int qi = qbase + qs;
  float y = b2[o];
#pragma unroll
  for (int c = 0; c < CH1; ++c) y = fmaf(me_lds[qs][c], W2[c*CH2 + o], y);
  float r = fmaf(s2s[o], y, s2h[o]);
  out[(size_t)qi*CH2 + o] = r > 0.f ? r : expm1f(r);
}

extern "C" void kernel_launch(void* const* d_in, const int* in_sizes, int n_in,
                              void* d_out, int out_size, void* d_ws, size_t ws_size,
                              hipStream_t stream) {
  const float* x      = (const float*)d_in[0];
  const float* W1     = (const float*)d_in[1];
  const float* b1     = (const float*)d_in[2];
  const float* gamma1 = (const float*)d_in[3];
  const float* beta1  = (const float*)d_in[4];
  const float* W2     = (const float*)d_in[5];
  const float* b2     = (const float*)d_in[6];
  const float* gamma2 = (const float*)d_in[7];
  const float* beta2  = (const float*)d_in[8];
  float* out = (float*)d_out;
  char* ws = (char*)d_ws;

  double* s1rep  = (double*)(ws + OFF_S1REP);
  double* stats2 = (double*)(ws + OFF_STATS2);
  float* sc1  = (float*)(ws + OFF_SC1);
  float* p    = (float*)(ws + OFF_P);
  float* minq = (float*)(ws + OFF_MINQ);

  hipMemsetAsync(ws, 0, 1280, stream);  // zero BN stat accumulators

  knn_kernel   <<<dim3(NBLK),       dim3(1024), 0, stream>>>(x, W1, b1, p, minq, s1rep);
  stage2_kernel<<<dim3(NB*NP/128),  dim3(128),  0, stream>>>(p, minq, s1rep, gamma1, beta1,
                                                             W2, b2, sc1, stats2);
  out_kernel   <<<dim3(NB*NP/8),    dim3(256),  0, stream>>>(p, minq, sc1, W2, b2,
                                                             stats2, gamma2, beta2, out);
}

// Round 5
// 236.933 us; speedup vs baseline: 1.2351x; 1.2351x over previous
//
#include <hip/hip_runtime.h>
#include <math.h>

namespace {
constexpr int NB = 16, NP = 2048, KNN = 32, CH1 = 6, CH2 = 32;
constexpr int QPB = 8;                  // queries (waves) per knn block
constexpr int NBLK = NB * NP / QPB;     // 4096 knn blocks
constexpr float BN_EPS = 1e-5f;

// workspace byte offsets
constexpr size_t OFF_S1REP  = 0;       // double[8][12] replicated BN1 accum (768 B)
constexpr size_t OFF_STATS2 = 768;     // double[64] (sum[32], sumsq[32])
constexpr size_t OFF_SC1    = 1280;    // float[12]
constexpr size_t OFF_P      = 2048;                                 // float[NB*NP*6]
constexpr size_t OFF_MINQ   = OFF_P + sizeof(float)*NB*NP*CH1;      // float[NB*NP*6]
}

// ---------------- DPP wave-64 reductions (VALU pipe, no LDS) ----------------
template <int C> __device__ __forceinline__ int dpp0i(int x) {
  return __builtin_amdgcn_update_dpp(0, x, C, 0xf, 0xf, true);
}
template <int C> __device__ __forceinline__ float dpp0f(float x) {
  return __uint_as_float((unsigned)__builtin_amdgcn_update_dpp(
      0, (int)__float_as_uint(x), C, 0xf, 0xf, true));
}
template <int C> __device__ __forceinline__ float dppInff(float x) {
  return __uint_as_float((unsigned)__builtin_amdgcn_update_dpp(
      0x7F800000, (int)__float_as_uint(x), C, 0xf, 0xf, false));
}
__device__ __forceinline__ int wave_isum_bcast(int x) {
  x += dpp0i<0x111>(x); x += dpp0i<0x112>(x); x += dpp0i<0x114>(x);
  x += dpp0i<0x118>(x); x += dpp0i<0x142>(x); x += dpp0i<0x143>(x);
  return __builtin_amdgcn_readlane(x, 63);
}
__device__ __forceinline__ float wave_fsum63(float x) {
  x += dpp0f<0x111>(x); x += dpp0f<0x112>(x); x += dpp0f<0x114>(x);
  x += dpp0f<0x118>(x); x += dpp0f<0x142>(x); x += dpp0f<0x143>(x);
  return x;
}
__device__ __forceinline__ float wave_fmin63(float x) {
  x = fminf(x, dppInff<0x111>(x)); x = fminf(x, dppInff<0x112>(x));
  x = fminf(x, dppInff<0x114>(x)); x = fminf(x, dppInff<0x118>(x));
  x = fminf(x, dppInff<0x142>(x)); x = fminf(x, dppInff<0x143>(x));
  return x;
}

#define BSEL(m, x, y) ((((x)) & (m)) | (((y)) & ~(m)))  // -> v_bfi

// Fused: pq + KNN select + per-query min(q) + BN1 replicated-atomic partials.
// One WAVE per query; 8 waves/block share one staged batch tile.
// launch_bounds(512,6): VGPR cap 85 — fits the 32-plane array with NO scratch
// spill (round-4's (1024,8) capped at 64 VGPR and spilled catastrophically).
__global__ __launch_bounds__(512, 6) void knn_kernel(const float* __restrict__ x,
                                                     const float* __restrict__ W1,
                                                     const float* __restrict__ b1,
                                                     float* __restrict__ pout,
                                                     float* __restrict__ minq,
                                                     double* __restrict__ s1rep) {
  __shared__ float4 pts[NP];      // x,y,z,|x|^2 (32 KiB)
  __shared__ float red[12][QPB];
  const int lane = threadIdx.x & 63;
  const int w    = threadIdx.x >> 6;
  const int qi   = blockIdx.x * QPB + w;   // 8 | 2048 -> same batch per block
  const int b    = qi >> 11;
  const int n    = qi & (NP - 1);

  const float* xb = x + (size_t)b * NP * 3;
  for (int j = threadIdx.x; j < NP; j += 512) {
    float a0 = xb[j*3+0], a1 = xb[j*3+1], a2 = xb[j*3+2];
    float sq = __fadd_rn(__fadd_rn(__fmul_rn(a0,a0), __fmul_rn(a1,a1)), __fmul_rn(a2,a2));
    pts[j] = make_float4(a0, a1, a2, sq);
  }
  __syncthreads();

  const float4 xq = pts[n];

  // distances, bit-exact vs reference formula. All d >= 0 for this data, so raw
  // float bits order correctly (sign plane unused by the select).
  unsigned a[32];
#pragma unroll
  for (int t = 0; t < 32; ++t) {
    float4 pj = pts[t*64 + lane];
    float dot = __fadd_rn(__fadd_rn(__fmul_rn(xq.x,pj.x), __fmul_rn(xq.y,pj.y)),
                          __fmul_rn(xq.z,pj.z));
    float d = __fsub_rn(__fadd_rn(xq.w, pj.w), __fmul_rn(2.0f, dot));
    a[31 - t] = __float_as_uint(d);
  }

  // 32x32 bit transpose, J=16 stage (full): after this the two 16-reg halves are
  // independent. Upper half -> planes of bits 31..16 (all we usually need).
#pragma unroll
  for (int g = 0; g < 16; ++g) {
    unsigned hi = a[g], lo = a[g+16];
    a[g]    = __builtin_amdgcn_perm(hi, lo, 0x07060302u);   // hi halves
    a[g+16] = __builtin_amdgcn_perm(hi, lo, 0x05040100u);   // lo halves
  }
  // upper half: J=8,4,2,1
#pragma unroll
  for (int g = 0; g < 8; ++g) {      // J=8
    unsigned hi = a[g], lo = a[g+8];
    a[g]   = __builtin_amdgcn_perm(hi, lo, 0x07030501u);
    a[g+8] = __builtin_amdgcn_perm(hi, lo, 0x06020400u);
  }
#pragma unroll
  for (int g = 0; g < 8; ++g) {      // J=4
    int k = (g >> 2)*8 + (g & 3);
    unsigned A = a[k], B = a[k+4];
    a[k]   = BSEL(0x0F0F0F0Fu, B >> 4, A);
    a[k+4] = BSEL(0xF0F0F0F0u, A << 4, B);
  }
#pragma unroll
  for (int g = 0; g < 8; ++g) {      // J=2
    int k = (g >> 1)*4 + (g & 1);
    unsigned A = a[k], B = a[k+2];
    a[k]   = BSEL(0x33333333u, B >> 2, A);
    a[k+2] = BSEL(0xCCCCCCCCu, A << 2, B);
  }
#pragma unroll
  for (int g = 0; g < 8; ++g) {      // J=1
    int k = g*2;
    unsigned A = a[k], B = a[k+1];
    a[k]   = BSEL(0x55555555u, B >> 1, A);
    a[k+1] = BSEL(0xAAAAAAAAu, A << 1, B);
  }
  // a[i] (i=1..15) = plane of distance bit (31-i); bit v <-> candidate v*64+lane

  // radix select on bits 30..16, tracking alive-count in SALU
  unsigned alive = 0xFFFFFFFFu, below = 0u;
  int rem = KNN, ca = 2048;
#pragma unroll
  for (int i = 1; i <= 15; ++i) {
    unsigned zeros = alive & ~a[i];
    int c0 = wave_isum_bcast(__popc(zeros));
    if (c0 >= rem) { alive = zeros; ca = c0; }
    else { rem -= c0; below |= zeros; alive &= a[i]; ca -= c0; }
  }
  unsigned sel = below;
  if (ca == rem) {
    sel |= alive;
  } else {
    // rare path: finish the lower-half transpose (planes of bits 15..0) lazily
#pragma unroll
    for (int g = 0; g < 8; ++g) {    // J=8, k in 16..23
      unsigned hi = a[16+g], lo = a[24+g];
      a[16+g] = __builtin_amdgcn_perm(hi, lo, 0x07030501u);
      a[24+g] = __builtin_amdgcn_perm(hi, lo, 0x06020400u);
    }
#pragma unroll
    for (int g = 0; g < 8; ++g) {    // J=4
      int k = 16 + (g >> 2)*8 + (g & 3);
      unsigned A = a[k], B = a[k+4];
      a[k]   = BSEL(0x0F0F0F0Fu, B >> 4, A);
      a[k+4] = BSEL(0xF0F0F0F0u, A << 4, B);
    }
#pragma unroll
    for (int g = 0; g < 8; ++g) {    // J=2
      int k = 16 + (g >> 1)*4 + (g & 1);
      unsigned A = a[k], B = a[k+2];
      a[k]   = BSEL(0x33333333u, B >> 2, A);
      a[k+2] = BSEL(0xCCCCCCCCu, A << 2, B);
    }
#pragma unroll
    for (int g = 0; g < 8; ++g) {    // J=1
      int k = 16 + g*2;
      unsigned A = a[k], B = a[k+1];
      a[k]   = BSEL(0x55555555u, B >> 1, A);
      a[k+1] = BSEL(0xAAAAAAAAu, A << 1, B);
    }
#pragma unroll
    for (int i = 16; i < 32; ++i) {  // extend radix onto bits 15..0 while unresolved
      if (ca != rem) {
        unsigned zeros = alive & ~a[i];
        int c0 = wave_isum_bcast(__popc(zeros));
        if (c0 >= rem) { alive = zeros; ca = c0; }
        else { rem -= c0; below |= zeros; alive &= a[i]; ca -= c0; }
      }
    }
    sel = below;
    if (ca == rem) {
      sel |= alive;
    } else {
      // bit-identical distances: take smallest indices j = v*64+lane
      for (int v = 0; v < 32; ++v) {
        if (rem <= 0) break;
        bool mine = (alive >> v) & 1;
        unsigned long long mb = __ballot(mine);
        int c = __popcll(mb);
        if (c <= rem) { if (mine) sel |= 1u << v; rem -= c; }
        else {
          if (mine && (int)__popcll(mb & ((1ull << lane) - 1)) < rem) sel |= 1u << v;
          rem = 0;
        }
      }
    }
  }

  // gather: sum/sumsq/min of q_j over selected neighbors (q from LDS pts + SGPR W1)
  float w3[CH1], w4[CH1], w5[CH1];
#pragma unroll
  for (int c = 0; c < CH1; ++c) { w3[c]=W1[3*CH1+c]; w4[c]=W1[4*CH1+c]; w5[c]=W1[5*CH1+c]; }
  float sq_[CH1], sqq[CH1], mn[CH1];
#pragma unroll
  for (int c = 0; c < CH1; ++c) { sq_[c] = 0.f; sqq[c] = 0.f; mn[c] = INFINITY; }
  unsigned m = sel;
  while (m) {
    int v = __builtin_ctz(m); m &= m - 1;
    float4 pj = pts[(v << 6) | lane];
#pragma unroll
    for (int c = 0; c < CH1; ++c) {
      float qv = pj.x*w3[c] + pj.y*w4[c] + pj.z*w5[c];   // contraction OK here
      sq_[c] += qv; sqq[c] += qv*qv; mn[c] = fminf(mn[c], qv);
    }
  }

  // p_i for this query (uniform across lanes)
  float pv[CH1];
#pragma unroll
  for (int c = 0; c < CH1; ++c) {
    float qv = xq.x*w3[c] + xq.y*w4[c] + xq.z*w5[c];
    pv[c] = b1[c] + xq.x*W1[c] + xq.y*W1[CH1+c] + xq.z*W1[2*CH1+c] + qv;
  }

#pragma unroll
  for (int c = 0; c < CH1; ++c) {
    float s  = wave_fsum63(sq_[c]);
    float s2 = wave_fsum63(sqq[c]);
    float mm = wave_fmin63(mn[c]);
    if (lane == 63) {
      minq[qi*CH1 + c] = mm;
      red[c][w]       = fmaf(32.f, pv[c], -s);                            // sum_k (p-q)
      red[CH1 + c][w] = fmaf(32.f, pv[c]*pv[c], fmaf(-2.f*pv[c], s, s2)); // sum_k (p-q)^2
    }
  }
  if (lane == 0) {
#pragma unroll
    for (int c = 0; c < CH1; ++c) pout[qi*CH1 + c] = pv[c];
  }
  __syncthreads();
  if (threadIdx.x < 12) {
    float s = 0.f;
#pragma unroll
    for (int ww = 0; ww < QPB; ++ww) s += red[threadIdx.x][ww];
    atomicAdd(s1rep + (blockIdx.x & 7) * 12 + threadIdx.x, (double)s);
  }
}

// stage2: derive sc1 from replicated BN1 stats (block 0 publishes it), apply
// max_k ELU(affine(p - q_j)) == ELU(affine(p - min_k q_j)), accumulate BN2 stats.
__global__ __launch_bounds__(128) void stage2_kernel(const float* __restrict__ p,
                                                     const float* __restrict__ minq,
                                                     const double* __restrict__ s1rep,
                                                     const float* __restrict__ gamma1,
                                                     const float* __restrict__ beta1,
                                                     const float* __restrict__ W2,
                                                     const float* __restrict__ b2,
                                                     float* __restrict__ sc1g,
                                                     double* __restrict__ stats2) {
  __shared__ double tot1[12];
  __shared__ float sc1s[12];
  __shared__ float rs[2][CH2], rq[2][CH2];
  const int t = threadIdx.x;
  if (t < 12) {
    double s = 0.0;
#pragma unroll
    for (int r = 0; r < 8; ++r) s += s1rep[r*12 + t];
    tot1[t] = s;
  }
  __syncthreads();
  if (t < CH1) {
    double cnt  = (double)NB * NP * KNN;
    double mean = tot1[t] / cnt;
    double var  = tot1[CH1 + t] / cnt - mean * mean;
    float scale = gamma1[t] / sqrtf((float)var + BN_EPS);
    sc1s[t] = scale; sc1s[CH1 + t] = beta1[t] - (float)mean * scale;
  }
  __syncthreads();
  if (blockIdx.x == 0 && t < 12) sc1g[t] = sc1s[t];

  const int qi = blockIdx.x * 128 + t;
  const int w = t >> 6, lane = t & 63;
  float me[CH1];
#pragma unroll
  for (int c = 0; c < CH1; ++c) {
    float v = fmaf(sc1s[c], p[qi*CH1 + c] - minq[qi*CH1 + c], sc1s[CH1 + c]);
    me[c] = v > 0.f ? v : expm1f(v);
  }
#pragma unroll
  for (int o = 0; o < CH2; ++o) {
    float y = b2[o];
#pragma unroll
    for (int c = 0; c < CH1; ++c) y = fmaf(me[c], W2[c*CH2 + o], y);
    float s  = wave_fsum63(y);
    float s2 = wave_fsum63(y * y);
    if (lane == 63) { rs[w][o] = s; rq[w][o] = s2; }
  }
  __syncthreads();
  if (t < CH2) atomicAdd(stats2 + t, (double)(rs[0][t] + rs[1][t]));
  else if (t < 2*CH2) atomicAdd(stats2 + t, (double)(rq[0][t-CH2] + rq[1][t-CH2]));
}

// final: derive sc2 per block, recompute y, apply BN2 + ELU. 8 queries/block.
__global__ __launch_bounds__(256) void out_kernel(const float* __restrict__ p,
                                                  const float* __restrict__ minq,
                                                  const float* __restrict__ sc1,
                                                  const float* __restrict__ W2,
                                                  const float* __restrict__ b2,
                                                  const double* __restrict__ stats2,
                                                  const float* __restrict__ gamma2,
                                                  const float* __restrict__ beta2,
                                                  float* __restrict__ out) {
  __shared__ float me_lds[8][CH1];
  __shared__ float s2s[CH2], s2h[CH2];
  const int t = threadIdx.x;
  if (t < CH2) {
    double cnt  = (double)NB * NP;
    double mean = stats2[t] / cnt;
    double var  = stats2[CH2 + t] / cnt - mean * mean;
    float scale = gamma2[t] / sqrtf((float)var + BN_EPS);
    s2s[t] = scale; s2h[t] = beta2[t] - (float)mean * scale;
  }
  const int qbase = blockIdx.x * 8;
  if (t < 48) {
    int qs = t / 6, c = t % 6;
    int qi = qbase + qs;
    float v = fmaf(sc1[c], p[qi*CH1 + c] - minq[qi*CH1 + c], sc1[CH1 + c]);
    me_lds[qs][c] = v > 0.f ? v : expm1f(v);
  }
  __syncthreads();
  const int qs = t >> 5, o = t & 31;
  const int qi = qbase + qs;
  float y = b2[o];
#pragma unroll
  for (int c = 0; c < CH1; ++c) y = fmaf(me_lds[qs][c], W2[c*CH2 + o], y);
  float r = fmaf(s2s[o], y, s2h[o]);
  out[(size_t)qi*CH2 + o] = r > 0.f ? r : expm1f(r);
}

extern "C" void kernel_launch(void* const* d_in, const int* in_sizes, int n_in,
                              void* d_out, int out_size, void* d_ws, size_t ws_size,
                              hipStream_t stream) {
  const float* x      = (const float*)d_in[0];
  const float* W1     = (const float*)d_in[1];
  const float* b1     = (const float*)d_in[2];
  const float* gamma1 = (const float*)d_in[3];
  const float* beta1  = (const float*)d_in[4];
  const float* W2     = (const float*)d_in[5];
  const float* b2     = (const float*)d_in[6];
  const float* gamma2 = (const float*)d_in[7];
  const float* beta2  = (const float*)d_in[8];
  float* out = (float*)d_out;
  char* ws = (char*)d_ws;

  double* s1rep  = (double*)(ws + OFF_S1REP);
  double* stats2 = (double*)(ws + OFF_STATS2);
  float* sc1  = (float*)(ws + OFF_SC1);
  float* p    = (float*)(ws + OFF_P);
  float* minq = (float*)(ws + OFF_MINQ);

  hipMemsetAsync(ws, 0, 1280, stream);  // zero BN stat accumulators

  knn_kernel   <<<dim3(NBLK),       dim3(512), 0, stream>>>(x, W1, b1, p, minq, s1rep);
  stage2_kernel<<<dim3(NB*NP/128),  dim3(128), 0, stream>>>(p, minq, s1rep, gamma1, beta1,
                                                            W2, b2, sc1, stats2);
  out_kernel   <<<dim3(NB*NP/8),    dim3(256), 0, stream>>>(p, minq, sc1, W2, b2,
                                                            stats2, gamma2, beta2, out);
}

// Round 6
// 93.997 us; speedup vs baseline: 3.1132x; 2.5206x over previous
//
#include <hip/hip_runtime.h>
#include <math.h>

namespace {
constexpr int NB = 16, NP = 2048, KNN = 32, CH1 = 6, CH2 = 32;
constexpr int QPB = 8;                  // queries (waves) per knn block
constexpr int NBLK = NB * NP / QPB;     // 4096 knn blocks
constexpr float BN_EPS = 1e-5f;

// workspace byte offsets
constexpr size_t OFF_S1REP  = 0;       // double[8][12] replicated BN1 accum (768 B)
constexpr size_t OFF_STATS2 = 768;     // double[64] (sum[32], sumsq[32])
constexpr size_t OFF_SC1    = 1280;    // float[12]
constexpr size_t OFF_P      = 2048;                                 // float[NB*NP*6]
constexpr size_t OFF_MINQ   = OFF_P + sizeof(float)*NB*NP*CH1;      // float[NB*NP*6]
}

// ---------------- DPP wave-64 reductions (VALU pipe, no LDS) ----------------
template <int C> __device__ __forceinline__ int dpp0i(int x) {
  return __builtin_amdgcn_update_dpp(0, x, C, 0xf, 0xf, true);
}
template <int C> __device__ __forceinline__ float dpp0f(float x) {
  return __uint_as_float((unsigned)__builtin_amdgcn_update_dpp(
      0, (int)__float_as_uint(x), C, 0xf, 0xf, true));
}
template <int C> __device__ __forceinline__ float dppInff(float x) {
  return __uint_as_float((unsigned)__builtin_amdgcn_update_dpp(
      0x7F800000, (int)__float_as_uint(x), C, 0xf, 0xf, false));
}
__device__ __forceinline__ int wave_isum_bcast(int x) {
  x += dpp0i<0x111>(x); x += dpp0i<0x112>(x); x += dpp0i<0x114>(x);
  x += dpp0i<0x118>(x); x += dpp0i<0x142>(x); x += dpp0i<0x143>(x);
  return __builtin_amdgcn_readlane(x, 63);
}
__device__ __forceinline__ float wave_fsum63(float x) {
  x += dpp0f<0x111>(x); x += dpp0f<0x112>(x); x += dpp0f<0x114>(x);
  x += dpp0f<0x118>(x); x += dpp0f<0x142>(x); x += dpp0f<0x143>(x);
  return x;
}
__device__ __forceinline__ float wave_fmin63(float x) {
  x = fminf(x, dppInff<0x111>(x)); x = fminf(x, dppInff<0x112>(x));
  x = fminf(x, dppInff<0x114>(x)); x = fminf(x, dppInff<0x118>(x));
  x = fminf(x, dppInff<0x142>(x)); x = fminf(x, dppInff<0x143>(x));
  return x;
}

#define BSEL(m, x, y) ((((x)) & (m)) | (((y)) & ~(m)))  // -> v_bfi

// Fused: pq + KNN select + per-query min(q) + BN1 replicated-atomic partials.
// One WAVE per query; 8 waves/block share one staged batch tile.
// Main path keeps only the 16 hi-bit planes live (h[16]); the rare tie path
// RECOMPUTES distances from LDS via volatile loads (blocks CSE) so nothing
// else stays live across the radix loop -> no scratch spill at (512,6).
__global__ __launch_bounds__(512, 6) void knn_kernel(const float* __restrict__ x,
                                                     const float* __restrict__ W1,
                                                     const float* __restrict__ b1,
                                                     float* __restrict__ pout,
                                                     float* __restrict__ minq,
                                                     double* __restrict__ s1rep) {
  __shared__ float4 pts[NP];      // x,y,z,|x|^2 (32 KiB)
  __shared__ float red[12][QPB];
  const int lane = threadIdx.x & 63;
  const int w    = threadIdx.x >> 6;
  const int qi   = blockIdx.x * QPB + w;   // 8 | 2048 -> same batch per block
  const int b    = qi >> 11;
  const int n    = qi & (NP - 1);

  const float* xb = x + (size_t)b * NP * 3;
  for (int j = threadIdx.x; j < NP; j += 512) {
    float a0 = xb[j*3+0], a1 = xb[j*3+1], a2 = xb[j*3+2];
    float sq = __fadd_rn(__fadd_rn(__fmul_rn(a0,a0), __fmul_rn(a1,a1)), __fmul_rn(a2,a2));
    pts[j] = make_float4(a0, a1, a2, sq);
  }
  __syncthreads();

  const float4 xq = pts[n];

  // distances, bit-exact vs reference formula; all d >= 0 so raw bits order.
  // d[31-t] = bits of candidate slot t (slot t <-> point t*64+lane).
  unsigned d[32];
#pragma unroll
  for (int t = 0; t < 32; ++t) {
    float4 pj = pts[t*64 + lane];
    float dot = __fadd_rn(__fadd_rn(__fmul_rn(xq.x,pj.x), __fmul_rn(xq.y,pj.y)),
                          __fmul_rn(xq.z,pj.z));
    float dd = __fsub_rn(__fadd_rn(xq.w, pj.w), __fmul_rn(2.0f, dot));
    d[31 - t] = __float_as_uint(dd);
  }

  // J=16 stage, HI HALF ONLY: h[g] = {d[g].hi16, d[g+16].hi16}. d[] dies here.
  unsigned h[16];
#pragma unroll
  for (int g = 0; g < 16; ++g)
    h[g] = __builtin_amdgcn_perm(d[g], d[g+16], 0x07060302u);
  // finish transpose of the hi half: J=8,4,2,1 on h[0..15]
#pragma unroll
  for (int g = 0; g < 8; ++g) {      // J=8
    unsigned hi = h[g], lo = h[g+8];
    h[g]   = __builtin_amdgcn_perm(hi, lo, 0x07030501u);
    h[g+8] = __builtin_amdgcn_perm(hi, lo, 0x06020400u);
  }
#pragma unroll
  for (int g = 0; g < 8; ++g) {      // J=4
    int k = (g >> 2)*8 + (g & 3);
    unsigned A = h[k], B = h[k+4];
    h[k]   = BSEL(0x0F0F0F0Fu, B >> 4, A);
    h[k+4] = BSEL(0xF0F0F0F0u, A << 4, B);
  }
#pragma unroll
  for (int g = 0; g < 8; ++g) {      // J=2
    int k = (g >> 1)*4 + (g & 1);
    unsigned A = h[k], B = h[k+2];
    h[k]   = BSEL(0x33333333u, B >> 2, A);
    h[k+2] = BSEL(0xCCCCCCCCu, A << 2, B);
  }
#pragma unroll
  for (int g = 0; g < 8; ++g) {      // J=1
    int k = g*2;
    unsigned A = h[k], B = h[k+1];
    h[k]   = BSEL(0x55555555u, B >> 1, A);
    h[k+1] = BSEL(0xAAAAAAAAu, A << 1, B);
  }
  // h[i] = plane of distance bit (31-i), i=0..15; bit v <-> candidate v*64+lane

  // radix select on bits 30..16 (h[1..15]), alive-count tracked in SALU
  unsigned alive = 0xFFFFFFFFu, below = 0u;
  int rem = KNN, ca = 2048;
#pragma unroll
  for (int i = 1; i <= 15; ++i) {
    unsigned zeros = alive & ~h[i];
    int c0 = wave_isum_bcast(__popc(zeros));
    if (c0 >= rem) { alive = zeros; ca = c0; }
    else { rem -= c0; below |= zeros; alive &= h[i]; ca -= c0; }
  }
  unsigned sel = below;
  if (__builtin_expect(ca == rem, 1)) {
    sel |= alive;
  } else {
    // RARE: recompute distances via volatile LDS reads (no CSE with main path),
    // build the LO-half planes l[0..15] (bits 15..0), extend the radix.
    unsigned e[32];
    const volatile float* vp = (const volatile float*)pts;
#pragma unroll
    for (int t = 0; t < 32; ++t) {
      int idx = (t*64 + lane) * 4;
      float px = vp[idx], py = vp[idx+1], pz = vp[idx+2], pw = vp[idx+3];
      float dot = __fadd_rn(__fadd_rn(__fmul_rn(xq.x,px), __fmul_rn(xq.y,py)),
                            __fmul_rn(xq.z,pz));
      float dd = __fsub_rn(__fadd_rn(xq.w, pw), __fmul_rn(2.0f, dot));
      e[31 - t] = __float_as_uint(dd);
    }
    unsigned l[16];
#pragma unroll
    for (int g = 0; g < 16; ++g)
      l[g] = __builtin_amdgcn_perm(e[g], e[g+16], 0x05040100u);
#pragma unroll
    for (int g = 0; g < 8; ++g) {    // J=8
      unsigned hi = l[g], lo = l[g+8];
      l[g]   = __builtin_amdgcn_perm(hi, lo, 0x07030501u);
      l[g+8] = __builtin_amdgcn_perm(hi, lo, 0x06020400u);
    }
#pragma unroll
    for (int g = 0; g < 8; ++g) {    // J=4
      int k = (g >> 2)*8 + (g & 3);
      unsigned A = l[k], B = l[k+4];
      l[k]   = BSEL(0x0F0F0F0Fu, B >> 4, A);
      l[k+4] = BSEL(0xF0F0F0F0u, A << 4, B);
    }
#pragma unroll
    for (int g = 0; g < 8; ++g) {    // J=2
      int k = (g >> 1)*4 + (g & 1);
      unsigned A = l[k], B = l[k+2];
      l[k]   = BSEL(0x33333333u, B >> 2, A);
      l[k+2] = BSEL(0xCCCCCCCCu, A << 2, B);
    }
#pragma unroll
    for (int g = 0; g < 8; ++g) {    // J=1
      int k = g*2;
      unsigned A = l[k], B = l[k+1];
      l[k]   = BSEL(0x55555555u, B >> 1, A);
      l[k+1] = BSEL(0xAAAAAAAAu, A << 1, B);
    }
    // l[i] = plane of distance bit (15-i); extend radix while unresolved
#pragma unroll
    for (int i = 0; i < 16; ++i) {
      if (ca != rem) {
        unsigned zeros = alive & ~l[i];
        int c0 = wave_isum_bcast(__popc(zeros));
        if (c0 >= rem) { alive = zeros; ca = c0; }
        else { rem -= c0; below |= zeros; alive &= l[i]; ca -= c0; }
      }
    }
    sel = below;
    if (ca == rem) {
      sel |= alive;
    } else {
      // bit-identical distances: take smallest indices j = v*64+lane
      for (int v = 0; v < 32; ++v) {
        if (rem <= 0) break;
        bool mine = (alive >> v) & 1;
        unsigned long long mb = __ballot(mine);
        int c = __popcll(mb);
        if (c <= rem) { if (mine) sel |= 1u << v; rem -= c; }
        else {
          if (mine && (int)__popcll(mb & ((1ull << lane) - 1)) < rem) sel |= 1u << v;
          rem = 0;
        }
      }
    }
  }

  // gather: sum/sumsq/min of q_j over selected neighbors (q from LDS pts + W1)
  float w3[CH1], w4[CH1], w5[CH1];
#pragma unroll
  for (int c = 0; c < CH1; ++c) { w3[c]=W1[3*CH1+c]; w4[c]=W1[4*CH1+c]; w5[c]=W1[5*CH1+c]; }
  float sq_[CH1], sqq[CH1], mn[CH1];
#pragma unroll
  for (int c = 0; c < CH1; ++c) { sq_[c] = 0.f; sqq[c] = 0.f; mn[c] = INFINITY; }
  unsigned m = sel;
  while (m) {
    int v = __builtin_ctz(m); m &= m - 1;
    float4 pj = pts[(v << 6) | lane];
#pragma unroll
    for (int c = 0; c < CH1; ++c) {
      float qv = pj.x*w3[c] + pj.y*w4[c] + pj.z*w5[c];   // contraction OK here
      sq_[c] += qv; sqq[c] += qv*qv; mn[c] = fminf(mn[c], qv);
    }
  }

  // p_i for this query (uniform across lanes)
  float pv[CH1];
#pragma unroll
  for (int c = 0; c < CH1; ++c) {
    float qv = xq.x*w3[c] + xq.y*w4[c] + xq.z*w5[c];
    pv[c] = b1[c] + xq.x*W1[c] + xq.y*W1[CH1+c] + xq.z*W1[2*CH1+c] + qv;
  }

#pragma unroll
  for (int c = 0; c < CH1; ++c) {
    float s  = wave_fsum63(sq_[c]);
    float s2 = wave_fsum63(sqq[c]);
    float mm = wave_fmin63(mn[c]);
    if (lane == 63) {
      minq[qi*CH1 + c] = mm;
      red[c][w]       = fmaf(32.f, pv[c], -s);                            // sum_k (p-q)
      red[CH1 + c][w] = fmaf(32.f, pv[c]*pv[c], fmaf(-2.f*pv[c], s, s2)); // sum_k (p-q)^2
    }
  }
  if (lane == 0) {
#pragma unroll
    for (int c = 0; c < CH1; ++c) pout[qi*CH1 + c] = pv[c];
  }
  __syncthreads();
  if (threadIdx.x < 12) {
    float s = 0.f;
#pragma unroll
    for (int ww = 0; ww < QPB; ++ww) s += red[threadIdx.x][ww];
    atomicAdd(s1rep + (blockIdx.x & 7) * 12 + threadIdx.x, (double)s);
  }
}

// stage2: derive sc1 from replicated BN1 stats (block 0 publishes it), apply
// max_k ELU(affine(p - q_j)) == ELU(affine(p - min_k q_j)), accumulate BN2 stats.
__global__ __launch_bounds__(128) void stage2_kernel(const float* __restrict__ p,
                                                     const float* __restrict__ minq,
                                                     const double* __restrict__ s1rep,
                                                     const float* __restrict__ gamma1,
                                                     const float* __restrict__ beta1,
                                                     const float* __restrict__ W2,
                                                     const float* __restrict__ b2,
                                                     float* __restrict__ sc1g,
                                                     double* __restrict__ stats2) {
  __shared__ double tot1[12];
  __shared__ float sc1s[12];
  __shared__ float rs[2][CH2], rq[2][CH2];
  const int t = threadIdx.x;
  if (t < 12) {
    double s = 0.0;
#pragma unroll
    for (int r = 0; r < 8; ++r) s += s1rep[r*12 + t];
    tot1[t] = s;
  }
  __syncthreads();
  if (t < CH1) {
    double cnt  = (double)NB * NP * KNN;
    double mean = tot1[t] / cnt;
    double var  = tot1[CH1 + t] / cnt - mean * mean;
    float scale = gamma1[t] / sqrtf((float)var + BN_EPS);
    sc1s[t] = scale; sc1s[CH1 + t] = beta1[t] - (float)mean * scale;
  }
  __syncthreads();
  if (blockIdx.x == 0 && t < 12) sc1g[t] = sc1s[t];

  const int qi = blockIdx.x * 128 + t;
  const int w = t >> 6, lane = t & 63;
  float me[CH1];
#pragma unroll
  for (int c = 0; c < CH1; ++c) {
    float v = fmaf(sc1s[c], p[qi*CH1 + c] - minq[qi*CH1 + c], sc1s[CH1 + c]);
    me[c] = v > 0.f ? v : expm1f(v);
  }
#pragma unroll
  for (int o = 0; o < CH2; ++o) {
    float y = b2[o];
#pragma unroll
    for (int c = 0; c < CH1; ++c) y = fmaf(me[c], W2[c*CH2 + o], y);
    float s  = wave_fsum63(y);
    float s2 = wave_fsum63(y * y);
    if (lane == 63) { rs[w][o] = s; rq[w][o] = s2; }
  }
  __syncthreads();
  if (t < CH2) atomicAdd(stats2 + t, (double)(rs[0][t] + rs[1][t]));
  else if (t < 2*CH2) atomicAdd(stats2 + t, (double)(rq[0][t-CH2] + rq[1][t-CH2]));
}

// final: derive sc2 per block, recompute y, apply BN2 + ELU. 8 queries/block.
__global__ __launch_bounds__(256) void out_kernel(const float* __restrict__ p,
                                                  const float* __restrict__ minq,
                                                  const float* __restrict__ sc1,
                                                  const float* __restrict__ W2,
                                                  const float* __restrict__ b2,
                                                  const double* __restrict__ stats2,
                                                  const float* __restrict__ gamma2,
                                                  const float* __restrict__ beta2,
                                                  float* __restrict__ out) {
  __shared__ float me_lds[8][CH1];
  __shared__ float s2s[CH2], s2h[CH2];
  const int t = threadIdx.x;
  if (t < CH2) {
    double cnt  = (double)NB * NP;
    double mean = stats2[t] / cnt;
    double var  = stats2[CH2 + t] / cnt - mean * mean;
    float scale = gamma2[t] / sqrtf((float)var + BN_EPS);
    s2s[t] = scale; s2h[t] = beta2[t] - (float)mean * scale;
  }
  const int qbase = blockIdx.x * 8;
  if (t < 48) {
    int qs = t / 6, c = t % 6;
    int qi = qbase + qs;
    float v = fmaf(sc1[c], p[qi*CH1 + c] - minq[qi*CH1 + c], sc1[CH1 + c]);
    me_lds[qs][c] = v > 0.f ? v : expm1f(v);
  }
  __syncthreads();
  const int qs = t >> 5, o = t & 31;
  const int qi = qbase + qs;
  float y = b2[o];
#pragma unroll
  for (int c = 0; c < CH1; ++c) y = fmaf(me_lds[qs][c], W2[c*CH2 + o], y);
  float r = fmaf(s2s[o], y, s2h[o]);
  out[(size_t)qi*CH2 + o] = r > 0.f ? r : expm1f(r);
}

extern "C" void kernel_launch(void* const* d_in, const int* in_sizes, int n_in,
                              void* d_out, int out_size, void* d_ws, size_t ws_size,
                              hipStream_t stream) {
  const float* x      = (const float*)d_in[0];
  const float* W1     = (const float*)d_in[1];
  const float* b1     = (const float*)d_in[2];
  const float* gamma1 = (const float*)d_in[3];
  const float* beta1  = (const float*)d_in[4];
  const float* W2     = (const float*)d_in[5];
  const float* b2     = (const float*)d_in[6];
  const float* gamma2 = (const float*)d_in[7];
  const float* beta2  = (const float*)d_in[8];
  float* out = (float*)d_out;
  char* ws = (char*)d_ws;

  double* s1rep  = (double*)(ws + OFF_S1REP);
  double* stats2 = (double*)(ws + OFF_STATS2);
  float* sc1  = (float*)(ws + OFF_SC1);
  float* p    = (float*)(ws + OFF_P);
  float* minq = (float*)(ws + OFF_MINQ);

  hipMemsetAsync(ws, 0, 1280, stream);  // zero BN stat accumulators

  knn_kernel   <<<dim3(NBLK),       dim3(512), 0, stream>>>(x, W1, b1, p, minq, s1rep);
  stage2_kernel<<<dim3(NB*NP/128),  dim3(128), 0, stream>>>(p, minq, s1rep, gamma1, beta1,
                                                            W2, b2, sc1, stats2);
  out_kernel   <<<dim3(NB*NP/8),    dim3(256), 0, stream>>>(p, minq, sc1, W2, b2,
                                                            stats2, gamma2, beta2, out);
}

// Round 7
// 81.950 us; speedup vs baseline: 3.5708x; 1.1470x over previous
//
#include <hip/hip_runtime.h>
#include <math.h>

namespace {
constexpr int NB = 16, NP = 2048, KNN = 32, CH1 = 6, CH2 = 32;
constexpr int QPB = 8;                  // queries (waves) per knn block
constexpr int NBLK = NB * NP / QPB;     // 4096 knn blocks
constexpr float BN_EPS = 1e-5f;

// workspace byte offsets
constexpr size_t OFF_S1REP  = 0;       // double[8][12] replicated BN1 accum (768 B)
constexpr size_t OFF_STATS2 = 768;     // double[64] (sum[32], sumsq[32])
constexpr size_t OFF_SC1    = 1280;    // float[12]
constexpr size_t OFF_P      = 2048;                                 // float[NB*NP*6]
constexpr size_t OFF_MINQ   = OFF_P + sizeof(float)*NB*NP*CH1;      // float[NB*NP*6]
}

typedef __attribute__((ext_vector_type(2))) float f32x2;

// packed fp32 (VOP3P, per-half IEEE RN — bit-identical to scalar mul/add)
__device__ __forceinline__ f32x2 pk_mul(f32x2 a, f32x2 b) {
  f32x2 d; asm("v_pk_mul_f32 %0, %1, %2" : "=v"(d) : "v"(a), "v"(b)); return d;
}
__device__ __forceinline__ f32x2 pk_add(f32x2 a, f32x2 b) {
  f32x2 d; asm("v_pk_add_f32 %0, %1, %2" : "=v"(d) : "v"(a), "v"(b)); return d;
}

// ---------------- DPP wave-64 reductions (VALU pipe, no LDS) ----------------
template <int C> __device__ __forceinline__ int dpp0i(int x) {
  return __builtin_amdgcn_update_dpp(0, x, C, 0xf, 0xf, true);
}
template <int C> __device__ __forceinline__ float dpp0f(float x) {
  return __uint_as_float((unsigned)__builtin_amdgcn_update_dpp(
      0, (int)__float_as_uint(x), C, 0xf, 0xf, true));
}
template <int C> __device__ __forceinline__ float dppInff(float x) {
  return __uint_as_float((unsigned)__builtin_amdgcn_update_dpp(
      0x7F800000, (int)__float_as_uint(x), C, 0xf, 0xf, false));
}
__device__ __forceinline__ int wave_isum_bcast(int x) {
  x += dpp0i<0x111>(x); x += dpp0i<0x112>(x); x += dpp0i<0x114>(x);
  x += dpp0i<0x118>(x); x += dpp0i<0x142>(x); x += dpp0i<0x143>(x);
  return __builtin_amdgcn_readlane(x, 63);
}
__device__ __forceinline__ float wave_fsum63(float x) {
  x += dpp0f<0x111>(x); x += dpp0f<0x112>(x); x += dpp0f<0x114>(x);
  x += dpp0f<0x118>(x); x += dpp0f<0x142>(x); x += dpp0f<0x143>(x);
  return x;
}
__device__ __forceinline__ float wave_fmin63(float x) {
  x = fminf(x, dppInff<0x111>(x)); x = fminf(x, dppInff<0x112>(x));
  x = fminf(x, dppInff<0x114>(x)); x = fminf(x, dppInff<0x118>(x));
  x = fminf(x, dppInff<0x142>(x)); x = fminf(x, dppInff<0x143>(x));
  return x;
}

#define BSEL(m, x, y) ((((x)) & (m)) | (((y)) & ~(m)))  // -> v_bfi

// Fused: pq + KNN select + per-query min(q) + BN1 replicated-atomic partials.
// One WAVE per query; 8 waves/block share one staged batch tile.
// LDS is structure-of-pairs: ptsX[k] = {x[k], x[k+1024]} etc, so the distance
// loop computes 2 candidates per v_pk op. Eager full 32-plane transpose
// (proven no-spill at (512,6)); early-exit guards on every radix round.
__global__ __launch_bounds__(512, 6) void knn_kernel(const float* __restrict__ x,
                                                     const float* __restrict__ W1,
                                                     const float* __restrict__ b1,
                                                     float* __restrict__ pout,
                                                     float* __restrict__ minq,
                                                     double* __restrict__ s1rep) {
  __shared__ f32x2 ptsX[NP/2], ptsY[NP/2], ptsZ[NP/2], ptsW[NP/2];  // 32 KiB
  __shared__ float red[12][QPB];
  const int lane = threadIdx.x & 63;
  const int w    = threadIdx.x >> 6;
  const int qi   = blockIdx.x * QPB + w;   // 8 | 2048 -> same batch per block
  const int b    = qi >> 11;
  const int n    = qi & (NP - 1);

  const float* xb = x + (size_t)b * NP * 3;
  for (int k = threadIdx.x; k < NP/2; k += 512) {
    const float* p0 = xb + k*3;
    const float* p1 = xb + (k + NP/2)*3;
    float a0=p0[0], a1=p0[1], a2=p0[2];
    float c0=p1[0], c1=p1[1], c2=p1[2];
    float sa = __fadd_rn(__fadd_rn(__fmul_rn(a0,a0), __fmul_rn(a1,a1)), __fmul_rn(a2,a2));
    float sc = __fadd_rn(__fadd_rn(__fmul_rn(c0,c0), __fmul_rn(c1,c1)), __fmul_rn(c2,c2));
    ptsX[k] = (f32x2){a0, c0};
    ptsY[k] = (f32x2){a1, c1};
    ptsZ[k] = (f32x2){a2, c2};
    ptsW[k] = (f32x2){sa, sc};
  }
  __syncthreads();

  // query point (n is wave-uniform)
  const int kq = n & (NP/2 - 1), hf = n >> 10;
  f32x2 tx = ptsX[kq], ty = ptsY[kq], tz = ptsZ[kq], tw = ptsW[kq];
  const float qx = hf ? tx.y : tx.x;
  const float qy = hf ? ty.y : ty.x;
  const float qz = hf ? tz.y : tz.x;
  const float qw = hf ? tw.y : tw.x;
  const f32x2 qx2 = {qx,qx}, qy2 = {qy,qy}, qz2 = {qz,qz}, qw2 = {qw,qw};

  // distances, bit-exact vs reference ((x*x + y*y) + z*z ; (sqi+sqj) - 2*dot,
  // 2*dot == dot+dot exactly). All d >= 0 so raw float bits order correctly.
  // d[31-s] = bits of slot s (slot s <-> candidate s*64+lane).
  unsigned d[32];
#pragma unroll
  for (int s = 0; s < 16; ++s) {
    int k = s*64 + lane;
    f32x2 X = ptsX[k], Y = ptsY[k], Z = ptsZ[k], W = ptsW[k];
    f32x2 dot = pk_add(pk_add(pk_mul(qx2, X), pk_mul(qy2, Y)), pk_mul(qz2, Z));
    f32x2 ss  = pk_add(qw2, W);
    f32x2 dt2 = pk_add(dot, dot);
    d[31 - s]  = __float_as_uint(__fsub_rn(ss.x, dt2.x));   // slot s
    d[15 - s]  = __float_as_uint(__fsub_rn(ss.y, dt2.y));   // slot s+16
  }

  // in-register 32x32 bit transpose (perm for byte stages, bfi for sub-byte)
#pragma unroll
  for (int g = 0; g < 16; ++g) {      // J=16
    unsigned hi = d[g], lo = d[g+16];
    d[g]    = __builtin_amdgcn_perm(hi, lo, 0x07060302u);
    d[g+16] = __builtin_amdgcn_perm(hi, lo, 0x05040100u);
  }
#pragma unroll
  for (int g = 0; g < 16; ++g) {      // J=8
    int k = (g >> 3)*16 + (g & 7);
    unsigned hi = d[k], lo = d[k+8];
    d[k]   = __builtin_amdgcn_perm(hi, lo, 0x07030501u);
    d[k+8] = __builtin_amdgcn_perm(hi, lo, 0x06020400u);
  }
#pragma unroll
  for (int g = 0; g < 16; ++g) {      // J=4
    int k = (g >> 2)*8 + (g & 3);
    unsigned A = d[k], B = d[k+4];
    d[k]   = BSEL(0x0F0F0F0Fu, B >> 4, A);
    d[k+4] = BSEL(0xF0F0F0F0u, A << 4, B);
  }
#pragma unroll
  for (int g = 0; g < 16; ++g) {      // J=2
    int k = (g >> 1)*4 + (g & 1);
    unsigned A = d[k], B = d[k+2];
    d[k]   = BSEL(0x33333333u, B >> 2, A);
    d[k+2] = BSEL(0xCCCCCCCCu, A << 2, B);
  }
#pragma unroll
  for (int g = 0; g < 16; ++g) {      // J=1
    int k = g*2;
    unsigned A = d[k], B = d[k+1];
    d[k]   = BSEL(0x55555555u, B >> 1, A);
    d[k+1] = BSEL(0xAAAAAAAAu, A << 1, B);
  }
  // d[i] = plane of distance bit (31-i); bit v of a plane <-> candidate v*64+lane

  // radix select on bits 30..16, SALU alive-count, early-exit per round
  unsigned alive = 0xFFFFFFFFu, below = 0u;
  int rem = KNN, ca = 2048;
#pragma unroll
  for (int i = 1; i <= 15; ++i) {
    if (ca != rem) {
      unsigned zeros = alive & ~d[i];
      int c0 = wave_isum_bcast(__popc(zeros));
      if (c0 >= rem) { alive = zeros; ca = c0; }
      else { rem -= c0; below |= zeros; alive &= d[i]; ca -= c0; }
    }
  }
  // extend onto bits 15..0 while unresolved (usually skipped)
#pragma unroll
  for (int i = 16; i < 32; ++i) {
    if (ca != rem) {
      unsigned zeros = alive & ~d[i];
      int c0 = wave_isum_bcast(__popc(zeros));
      if (c0 >= rem) { alive = zeros; ca = c0; }
      else { rem -= c0; below |= zeros; alive &= d[i]; ca -= c0; }
    }
  }
  unsigned sel = below;
  if (ca == rem) {
    sel |= alive;
  } else {
    // bit-identical distances: take smallest indices j = v*64+lane (v-major)
    for (int v = 0; v < 32; ++v) {
      if (rem <= 0) break;
      bool mine = (alive >> v) & 1;
      unsigned long long mb = __ballot(mine);
      int c = __popcll(mb);
      if (c <= rem) { if (mine) sel |= 1u << v; rem -= c; }
      else {
        if (mine && (int)__popcll(mb & ((1ull << lane) - 1)) < rem) sel |= 1u << v;
        rem = 0;
      }
    }
  }

  // gather: sum/sumsq/min of q_j over selected neighbors (pair LDS + half select)
  float w3[CH1], w4[CH1], w5[CH1];
#pragma unroll
  for (int c = 0; c < CH1; ++c) { w3[c]=W1[3*CH1+c]; w4[c]=W1[4*CH1+c]; w5[c]=W1[5*CH1+c]; }
  float sq_[CH1], sqq[CH1], mn[CH1];
#pragma unroll
  for (int c = 0; c < CH1; ++c) { sq_[c] = 0.f; sqq[c] = 0.f; mn[c] = INFINITY; }
  unsigned m = sel;
  while (m) {
    int v = __builtin_ctz(m); m &= m - 1;
    int j = (v << 6) | lane;
    int kk = j & (NP/2 - 1);
    bool hi = v >= 16;
    f32x2 gx = ptsX[kk], gy = ptsY[kk], gz = ptsZ[kk];
    float px_ = hi ? gx.y : gx.x;
    float py_ = hi ? gy.y : gy.x;
    float pz_ = hi ? gz.y : gz.x;
#pragma unroll
    for (int c = 0; c < CH1; ++c) {
      float qv = px_*w3[c] + py_*w4[c] + pz_*w5[c];   // contraction OK here
      sq_[c] += qv; sqq[c] += qv*qv; mn[c] = fminf(mn[c], qv);
    }
  }

  // p_i for this query (uniform across lanes)
  float pv[CH1];
#pragma unroll
  for (int c = 0; c < CH1; ++c) {
    float qv = qx*w3[c] + qy*w4[c] + qz*w5[c];
    pv[c] = b1[c] + qx*W1[c] + qy*W1[CH1+c] + qz*W1[2*CH1+c] + qv;
  }

#pragma unroll
  for (int c = 0; c < CH1; ++c) {
    float s  = wave_fsum63(sq_[c]);
    float s2 = wave_fsum63(sqq[c]);
    float mm = wave_fmin63(mn[c]);
    if (lane == 63) {
      minq[qi*CH1 + c] = mm;
      red[c][w]       = fmaf(32.f, pv[c], -s);                            // sum_k (p-q)
      red[CH1 + c][w] = fmaf(32.f, pv[c]*pv[c], fmaf(-2.f*pv[c], s, s2)); // sum_k (p-q)^2
    }
  }
  if (lane == 0) {
#pragma unroll
    for (int c = 0; c < CH1; ++c) pout[qi*CH1 + c] = pv[c];
  }
  __syncthreads();
  if (threadIdx.x < 12) {
    float s = 0.f;
#pragma unroll
    for (int ww = 0; ww < QPB; ++ww) s += red[threadIdx.x][ww];
    atomicAdd(s1rep + (blockIdx.x & 7) * 12 + threadIdx.x, (double)s);
  }
}

// stage2: derive sc1 from replicated BN1 stats (block 0 publishes it), apply
// max_k ELU(affine(p - q_j)) == ELU(affine(p - min_k q_j)), accumulate BN2 stats.
__global__ __launch_bounds__(128) void stage2_kernel(const float* __restrict__ p,
                                                     const float* __restrict__ minq,
                                                     const double* __restrict__ s1rep,
                                                     const float* __restrict__ gamma1,
                                                     const float* __restrict__ beta1,
                                                     const float* __restrict__ W2,
                                                     const float* __restrict__ b2,
                                                     float* __restrict__ sc1g,
                                                     double* __restrict__ stats2) {
  __shared__ double tot1[12];
  __shared__ float sc1s[12];
  __shared__ float rs[2][CH2], rq[2][CH2];
  const int t = threadIdx.x;
  if (t < 12) {
    double s = 0.0;
#pragma unroll
    for (int r = 0; r < 8; ++r) s += s1rep[r*12 + t];
    tot1[t] = s;
  }
  __syncthreads();
  if (t < CH1) {
    double cnt  = (double)NB * NP * KNN;
    double mean = tot1[t] / cnt;
    double var  = tot1[CH1 + t] / cnt - mean * mean;
    float scale = gamma1[t] / sqrtf((float)var + BN_EPS);
    sc1s[t] = scale; sc1s[CH1 + t] = beta1[t] - (float)mean * scale;
  }
  __syncthreads();
  if (blockIdx.x == 0 && t < 12) sc1g[t] = sc1s[t];

  const int qi = blockIdx.x * 128 + t;
  const int w = t >> 6, lane = t & 63;
  float me[CH1];
#pragma unroll
  for (int c = 0; c < CH1; ++c) {
    float v = fmaf(sc1s[c], p[qi*CH1 + c] - minq[qi*CH1 + c], sc1s[CH1 + c]);
    me[c] = v > 0.f ? v : expm1f(v);
  }
#pragma unroll
  for (int o = 0; o < CH2; ++o) {
    float y = b2[o];
#pragma unroll
    for (int c = 0; c < CH1; ++c) y = fmaf(me[c], W2[c*CH2 + o], y);
    float s  = wave_fsum63(y);
    float s2 = wave_fsum63(y * y);
    if (lane == 63) { rs[w][o] = s; rq[w][o] = s2; }
  }
  __syncthreads();
  if (t < CH2) atomicAdd(stats2 + t, (double)(rs[0][t] + rs[1][t]));
  else if (t < 2*CH2) atomicAdd(stats2 + t, (double)(rq[0][t-CH2] + rq[1][t-CH2]));
}

// final: derive sc2 per block, recompute y, apply BN2 + ELU. 8 queries/block.
__global__ __launch_bounds__(256) void out_kernel(const float* __restrict__ p,
                                                  const float* __restrict__ minq,
                                                  const float* __restrict__ sc1,
                                                  const float* __restrict__ W2,
                                                  const float* __restrict__ b2,
                                                  const double* __restrict__ stats2,
                                                  const float* __restrict__ gamma2,
                                                  const float* __restrict__ beta2,
                                                  float* __restrict__ out) {
  __shared__ float me_lds[8][CH1];
  __shared__ float s2s[CH2], s2h[CH2];
  const int t = threadIdx.x;
  if (t < CH2) {
    double cnt  = (double)NB * NP;
    double mean = stats2[t] / cnt;
    double var  = stats2[CH2 + t] / cnt - mean * mean;
    float scale = gamma2[t] / sqrtf((float)var + BN_EPS);
    s2s[t] = scale; s2h[t] = beta2[t] - (float)mean * scale;
  }
  const int qbase = blockIdx.x * 8;
  if (t < 48) {
    int qs = t / 6, c = t % 6;
    int qi = qbase + qs;
    float v = fmaf(sc1[c], p[qi*CH1 + c] - minq[qi*CH1 + c], sc1[CH1 + c]);
    me_lds[qs][c] = v > 0.f ? v : expm1f(v);
  }
  __syncthreads();
  const int qs = t >> 5, o = t & 31;
  const int qi = qbase + qs;
  float y = b2[o];
#pragma unroll
  for (int c = 0; c < CH1; ++c) y = fmaf(me_lds[qs][c], W2[c*CH2 + o], y);
  float r = fmaf(s2s[o], y, s2h[o]);
  out[(size_t)qi*CH2 + o] = r > 0.f ? r : expm1f(r);
}

extern "C" void kernel_launch(void* const* d_in, const int* in_sizes, int n_in,
                              void* d_out, int out_size, void* d_ws, size_t ws_size,
                              hipStream_t stream) {
  const float* x      = (const float*)d_in[0];
  const float* W1     = (const float*)d_in[1];
  const float* b1     = (const float*)d_in[2];
  const float* gamma1 = (const float*)d_in[3];
  const float* beta1  = (const float*)d_in[4];
  const float* W2     = (const float*)d_in[5];
  const float* b2     = (const float*)d_in[6];
  const float* gamma2 = (const float*)d_in[7];
  const float* beta2  = (const float*)d_in[8];
  float* out = (float*)d_out;
  char* ws = (char*)d_ws;

  double* s1rep  = (double*)(ws + OFF_S1REP);
  double* stats2 = (double*)(ws + OFF_STATS2);
  float* sc1  = (float*)(ws + OFF_SC1);
  float* p    = (float*)(ws + OFF_P);
  float* minq = (float*)(ws + OFF_MINQ);

  hipMemsetAsync(ws, 0, 1280, stream);  // zero BN stat accumulators

  knn_kernel   <<<dim3(NBLK),       dim3(512), 0, stream>>>(x, W1, b1, p, minq, s1rep);
  stage2_kernel<<<dim3(NB*NP/128),  dim3(128), 0, stream>>>(p, minq, s1rep, gamma1, beta1,
                                                            W2, b2, sc1, stats2);
  out_kernel   <<<dim3(NB*NP/8),    dim3(256), 0, stream>>>(p, minq, sc1, W2, b2,
                                                            stats2, gamma2, beta2, out);
}

// Round 8
// 81.880 us; speedup vs baseline: 3.5739x; 1.0009x over previous
//
#include <hip/hip_runtime.h>
#include <math.h>

namespace {
constexpr int NB = 16, NP = 2048, KNN = 32, CH1 = 6, CH2 = 32;
constexpr int QPB = 8;                  // queries (waves) per knn block
constexpr int NBLK = NB * NP / QPB;     // 4096 knn blocks
constexpr float BN_EPS = 1e-5f;

// workspace byte offsets
constexpr size_t OFF_S1REP  = 0;       // double[8][12] replicated BN1 accum (768 B)
constexpr size_t OFF_STATS2 = 768;     // double[64] (sum[32], sumsq[32])
constexpr size_t OFF_SC1    = 1280;    // float[12]
constexpr size_t OFF_P      = 2048;                                 // float[NB*NP*6]
constexpr size_t OFF_MINQ   = OFF_P + sizeof(float)*NB*NP*CH1;      // float[NB*NP*6]
}

typedef __attribute__((ext_vector_type(2))) float f32x2;

// packed fp32 (VOP3P, per-half IEEE RN — bit-identical to scalar mul/add)
__device__ __forceinline__ f32x2 pk_mul(f32x2 a, f32x2 b) {
  f32x2 d; asm("v_pk_mul_f32 %0, %1, %2" : "=v"(d) : "v"(a), "v"(b)); return d;
}
__device__ __forceinline__ f32x2 pk_add(f32x2 a, f32x2 b) {
  f32x2 d; asm("v_pk_add_f32 %0, %1, %2" : "=v"(d) : "v"(a), "v"(b)); return d;
}

// ---------------- DPP wave-64 reductions (VALU pipe, no LDS) ----------------
template <int C> __device__ __forceinline__ int dpp0i(int x) {
  return __builtin_amdgcn_update_dpp(0, x, C, 0xf, 0xf, true);
}
template <int C> __device__ __forceinline__ float dpp0f(float x) {
  return __uint_as_float((unsigned)__builtin_amdgcn_update_dpp(
      0, (int)__float_as_uint(x), C, 0xf, 0xf, true));
}
template <int C> __device__ __forceinline__ float dppInff(float x) {
  return __uint_as_float((unsigned)__builtin_amdgcn_update_dpp(
      0x7F800000, (int)__float_as_uint(x), C, 0xf, 0xf, false));
}
__device__ __forceinline__ int wave_isum_bcast(int x) {
  x += dpp0i<0x111>(x); x += dpp0i<0x112>(x); x += dpp0i<0x114>(x);
  x += dpp0i<0x118>(x); x += dpp0i<0x142>(x); x += dpp0i<0x143>(x);
  return __builtin_amdgcn_readlane(x, 63);
}
// inclusive prefix sum over 64 lanes (same stage set; scan semantics)
__device__ __forceinline__ int wave_iscan_incl(int x) {
  x += dpp0i<0x111>(x); x += dpp0i<0x112>(x); x += dpp0i<0x114>(x);
  x += dpp0i<0x118>(x); x += dpp0i<0x142>(x); x += dpp0i<0x143>(x);
  return x;
}
__device__ __forceinline__ float wave_fsum63(float x) {
  x += dpp0f<0x111>(x); x += dpp0f<0x112>(x); x += dpp0f<0x114>(x);
  x += dpp0f<0x118>(x); x += dpp0f<0x142>(x); x += dpp0f<0x143>(x);
  return x;
}
__device__ __forceinline__ float wave_fmin63(float x) {
  x = fminf(x, dppInff<0x111>(x)); x = fminf(x, dppInff<0x112>(x));
  x = fminf(x, dppInff<0x114>(x)); x = fminf(x, dppInff<0x118>(x));
  x = fminf(x, dppInff<0x142>(x)); x = fminf(x, dppInff<0x143>(x));
  return x;
}

#define BSEL(m, x, y) ((((x)) & (m)) | (((y)) & ~(m)))  // -> v_bfi

// physical slot for chunk m: XOR-swizzle low 3 bits by reader-lane bits
__device__ __forceinline__ int swz(int m) { return (m & ~7) | ((m ^ (m >> 3)) & 7); }

// Fused: pq + KNN select + per-query min(q) + BN1 replicated-atomic partials.
// One WAVE per query; 8 waves/block share one staged batch tile.
// Candidate mapping: j = 32*lane + v (lane-local consecutive). LDS = chunked
// SoA float4 (4 consecutive points per chunk) at XOR-swizzled physical slots:
// per 4 candidates -> 4 ds_read_b128 + 14 pk ops. Eager full 32-plane
// transpose (proven no-spill); early-exit radix guards from round 7.
__global__ __launch_bounds__(512, 6) void knn_kernel(const float* __restrict__ x,
                                                     const float* __restrict__ W1,
                                                     const float* __restrict__ b1,
                                                     float* __restrict__ pout,
                                                     float* __restrict__ minq,
                                                     double* __restrict__ s1rep) {
  __shared__ float4 pts4[4 * 512];   // X[512] | Y[512] | Z[512] | W[512], 32 KiB
  __shared__ float red[12][QPB];
  const int lane = threadIdx.x & 63;
  const int w    = threadIdx.x >> 6;
  const int qi   = blockIdx.x * QPB + w;   // 8 | 2048 -> same batch per block
  const int b    = qi >> 11;
  const int n    = qi & (NP - 1);
  const int s7   = lane & 7;

  const float* xb = x + (size_t)b * NP * 3;
  {
    const int t = threadIdx.x;               // one chunk (4 points) per thread
    const float4* g4 = (const float4*)xb;
    float4 f0 = g4[t*3], f1 = g4[t*3+1], f2 = g4[t*3+2];
    float4 X = {f0.x, f0.w, f1.z, f2.y};
    float4 Y = {f0.y, f1.x, f1.w, f2.z};
    float4 Z = {f0.z, f1.y, f2.x, f2.w};
    float4 Wv;
    Wv.x = __fadd_rn(__fadd_rn(__fmul_rn(X.x,X.x), __fmul_rn(Y.x,Y.x)), __fmul_rn(Z.x,Z.x));
    Wv.y = __fadd_rn(__fadd_rn(__fmul_rn(X.y,X.y), __fmul_rn(Y.y,Y.y)), __fmul_rn(Z.y,Z.y));
    Wv.z = __fadd_rn(__fadd_rn(__fmul_rn(X.z,X.z), __fmul_rn(Y.z,Y.z)), __fmul_rn(Z.z,Z.z));
    Wv.w = __fadd_rn(__fadd_rn(__fmul_rn(X.w,X.w), __fmul_rn(Y.w,Y.w)), __fmul_rn(Z.w,Z.w));
    const int ph = swz(t);
    pts4[ph] = X; pts4[512+ph] = Y; pts4[1024+ph] = Z; pts4[1536+ph] = Wv;
  }
  __syncthreads();

  // query coords (wave-uniform)
  const float* ps = (const float*)pts4;
  const int fq = swz(n >> 2) * 4 + (n & 3);
  const float qx = ps[fq], qy = ps[2048+fq], qz = ps[4096+fq], qw = ps[6144+fq];
  const f32x2 qx2 = {qx,qx}, qy2 = {qy,qy}, qz2 = {qz,qz}, qw2 = {qw,qw};

  // distances, bit-exact vs reference ((x*x+y*y)+z*z ; (sqi+sqj) - (dot+dot)).
  // All d >= 0 so raw float bits order. d[31-v] = bits of candidate 32*lane+v.
  unsigned d[32];
#pragma unroll
  for (int g = 0; g < 8; ++g) {
    const int ph = lane*8 + (g ^ s7);
    float4 X = pts4[ph], Y = pts4[512+ph], Z = pts4[1024+ph], Wv = pts4[1536+ph];
    f32x2 x01 = {X.x,X.y}, y01 = {Y.x,Y.y}, z01 = {Z.x,Z.y}, w01 = {Wv.x,Wv.y};
    f32x2 x23 = {X.z,X.w}, y23 = {Y.z,Y.w}, z23 = {Z.z,Z.w}, w23 = {Wv.z,Wv.w};
    f32x2 dotA = pk_add(pk_add(pk_mul(qx2,x01), pk_mul(qy2,y01)), pk_mul(qz2,z01));
    f32x2 dotB = pk_add(pk_add(pk_mul(qx2,x23), pk_mul(qy2,y23)), pk_mul(qz2,z23));
    f32x2 ssA = pk_add(qw2, w01), ssB = pk_add(qw2, w23);
    f32x2 dA = pk_add(dotA, dotA), dB = pk_add(dotB, dotB);
    d[31-(4*g+0)] = __float_as_uint(__fsub_rn(ssA.x, dA.x));
    d[31-(4*g+1)] = __float_as_uint(__fsub_rn(ssA.y, dA.y));
    d[31-(4*g+2)] = __float_as_uint(__fsub_rn(ssB.x, dB.x));
    d[31-(4*g+3)] = __float_as_uint(__fsub_rn(ssB.y, dB.y));
  }

  // in-register 32x32 bit transpose (perm for byte stages, bfi for sub-byte)
#pragma unroll
  for (int g = 0; g < 16; ++g) {      // J=16
    unsigned hi = d[g], lo = d[g+16];
    d[g]    = __builtin_amdgcn_perm(hi, lo, 0x07060302u);
    d[g+16] = __builtin_amdgcn_perm(hi, lo, 0x05040100u);
  }
#pragma unroll
  for (int g = 0; g < 16; ++g) {      // J=8
    int k = (g >> 3)*16 + (g & 7);
    unsigned hi = d[k], lo = d[k+8];
    d[k]   = __builtin_amdgcn_perm(hi, lo, 0x07030501u);
    d[k+8] = __builtin_amdgcn_perm(hi, lo, 0x06020400u);
  }
#pragma unroll
  for (int g = 0; g < 16; ++g) {      // J=4
    int k = (g >> 2)*8 + (g & 3);
    unsigned A = d[k], B = d[k+4];
    d[k]   = BSEL(0x0F0F0F0Fu, B >> 4, A);
    d[k+4] = BSEL(0xF0F0F0F0u, A << 4, B);
  }
#pragma unroll
  for (int g = 0; g < 16; ++g) {      // J=2
    int k = (g >> 1)*4 + (g & 1);
    unsigned A = d[k], B = d[k+2];
    d[k]   = BSEL(0x33333333u, B >> 2, A);
    d[k+2] = BSEL(0xCCCCCCCCu, A << 2, B);
  }
#pragma unroll
  for (int g = 0; g < 16; ++g) {      // J=1
    int k = g*2;
    unsigned A = d[k], B = d[k+1];
    d[k]   = BSEL(0x55555555u, B >> 1, A);
    d[k+1] = BSEL(0xAAAAAAAAu, A << 1, B);
  }
  // d[i] = plane of distance bit (31-i); bit v of a plane <-> candidate 32*lane+v

  // radix select on bits 30..16 then (rarely) 15..0; SALU alive-count;
  // early-exit guards from round 7 (alive can't reach 32 before that).
  unsigned alive = 0xFFFFFFFFu, below = 0u;
  int rem = KNN, ca = 2048;
#pragma unroll
  for (int i = 1; i <= 6; ++i) {
    unsigned zeros = BSEL(d[i], 0u, alive);     // alive & ~plane
    int c0 = wave_isum_bcast(__popc(zeros));
    if (c0 >= rem) { alive = zeros; ca = c0; }
    else { rem -= c0; below |= zeros; alive &= d[i]; ca -= c0; }
  }
#pragma unroll
  for (int i = 7; i < 32; ++i) {
    if (ca != rem) {
      unsigned zeros = BSEL(d[i], 0u, alive);
      int c0 = wave_isum_bcast(__popc(zeros));
      if (c0 >= rem) { alive = zeros; ca = c0; }
      else { rem -= c0; below |= zeros; alive &= d[i]; ca -= c0; }
    }
  }
  unsigned sel = below;
  if (ca == rem) {
    sel |= alive;
  } else {
    // bit-identical distances: smallest j = 32*lane + v -> lane-major order.
    // exclusive prefix of per-lane tie counts; lane takes its lowest bits.
    int cnt  = __popc(alive);
    int excl = wave_iscan_incl(cnt) - cnt;
    int k = rem - excl;
    k = k < 0 ? 0 : (k > cnt ? cnt : k);
    while (k > 0) {
      unsigned bb = alive & (unsigned)(-(int)alive);
      sel |= bb; alive ^= bb; --k;
    }
  }

  // gather: sum/sumsq/min of q_j over selected neighbors (chunked LDS reads)
  float w3[CH1], w4[CH1], w5[CH1];
#pragma unroll
  for (int c = 0; c < CH1; ++c) { w3[c]=W1[3*CH1+c]; w4[c]=W1[4*CH1+c]; w5[c]=W1[5*CH1+c]; }
  float sq_[CH1], sqq[CH1], mn[CH1];
#pragma unroll
  for (int c = 0; c < CH1; ++c) { sq_[c] = 0.f; sqq[c] = 0.f; mn[c] = INFINITY; }
  unsigned m = sel;
  while (m) {
    int v = __builtin_ctz(m); m &= m - 1;
    int fi = (lane*8 + ((v >> 2) ^ s7)) * 4 + (v & 3);
    float px_ = ps[fi], py_ = ps[2048+fi], pz_ = ps[4096+fi];
#pragma unroll
    for (int c = 0; c < CH1; ++c) {
      float qv = px_*w3[c] + py_*w4[c] + pz_*w5[c];   // contraction OK here
      sq_[c] += qv; sqq[c] += qv*qv; mn[c] = fminf(mn[c], qv);
    }
  }

  // p_i for this query (uniform across lanes)
  float pv[CH1];
#pragma unroll
  for (int c = 0; c < CH1; ++c) {
    float qv = qx*w3[c] + qy*w4[c] + qz*w5[c];
    pv[c] = b1[c] + qx*W1[c] + qy*W1[CH1+c] + qz*W1[2*CH1+c] + qv;
  }

#pragma unroll
  for (int c = 0; c < CH1; ++c) {
    float s  = wave_fsum63(sq_[c]);
    float s2 = wave_fsum63(sqq[c]);
    float mm = wave_fmin63(mn[c]);
    if (lane == 63) {
      minq[qi*CH1 + c] = mm;
      red[c][w]       = fmaf(32.f, pv[c], -s);                            // sum_k (p-q)
      red[CH1 + c][w] = fmaf(32.f, pv[c]*pv[c], fmaf(-2.f*pv[c], s, s2)); // sum_k (p-q)^2
    }
  }
  if (lane == 0) {
#pragma unroll
    for (int c = 0; c < CH1; ++c) pout[qi*CH1 + c] = pv[c];
  }
  __syncthreads();
  if (threadIdx.x < 12) {
    float s = 0.f;
#pragma unroll
    for (int ww = 0; ww < QPB; ++ww) s += red[threadIdx.x][ww];
    atomicAdd(s1rep + (blockIdx.x & 7) * 12 + threadIdx.x, (double)s);
  }
}

// stage2: derive sc1 from replicated BN1 stats (block 0 publishes it), apply
// max_k ELU(affine(p - q_j)) == ELU(affine(p - min_k q_j)), accumulate BN2 stats.
__global__ __launch_bounds__(128) void stage2_kernel(const float* __restrict__ p,
                                                     const float* __restrict__ minq,
                                                     const double* __restrict__ s1rep,
                                                     const float* __restrict__ gamma1,
                                                     const float* __restrict__ beta1,
                                                     const float* __restrict__ W2,
                                                     const float* __restrict__ b2,
                                                     float* __restrict__ sc1g,
                                                     double* __restrict__ stats2) {
  __shared__ double tot1[12];
  __shared__ float sc1s[12];
  __shared__ float rs[2][CH2], rq[2][CH2];
  const int t = threadIdx.x;
  if (t < 12) {
    double s = 0.0;
#pragma unroll
    for (int r = 0; r < 8; ++r) s += s1rep[r*12 + t];
    tot1[t] = s;
  }
  __syncthreads();
  if (t < CH1) {
    double cnt  = (double)NB * NP * KNN;
    double mean = tot1[t] / cnt;
    double var  = tot1[CH1 + t] / cnt - mean * mean;
    float scale = gamma1[t] / sqrtf((float)var + BN_EPS);
    sc1s[t] = scale; sc1s[CH1 + t] = beta1[t] - (float)mean * scale;
  }
  __syncthreads();
  if (blockIdx.x == 0 && t < 12) sc1g[t] = sc1s[t];

  const int qi = blockIdx.x * 128 + t;
  const int w = t >> 6, lane = t & 63;
  float me[CH1];
#pragma unroll
  for (int c = 0; c < CH1; ++c) {
    float v = fmaf(sc1s[c], p[qi*CH1 + c] - minq[qi*CH1 + c], sc1s[CH1 + c]);
    me[c] = v > 0.f ? v : expm1f(v);
  }
#pragma unroll
  for (int o = 0; o < CH2; ++o) {
    float y = b2[o];
#pragma unroll
    for (int c = 0; c < CH1; ++c) y = fmaf(me[c], W2[c*CH2 + o], y);
    float s  = wave_fsum63(y);
    float s2 = wave_fsum63(y * y);
    if (lane == 63) { rs[w][o] = s; rq[w][o] = s2; }
  }
  __syncthreads();
  if (t < CH2) atomicAdd(stats2 + t, (double)(rs[0][t] + rs[1][t]));
  else if (t < 2*CH2) atomicAdd(stats2 + t, (double)(rq[0][t-CH2] + rq[1][t-CH2]));
}

// final: derive sc2 per block, recompute y, apply BN2 + ELU. 8 queries/block.
__global__ __launch_bounds__(256) void out_kernel(const float* __restrict__ p,
                                                  const float* __restrict__ minq,
                                                  const float* __restrict__ sc1,
                                                  const float* __restrict__ W2,
                                                  const float* __restrict__ b2,
                                                  const double* __restrict__ stats2,
                                                  const float* __restrict__ gamma2,
                                                  const float* __restrict__ beta2,
                                                  float* __restrict__ out) {
  __shared__ float me_lds[8][CH1];
  __shared__ float s2s[CH2], s2h[CH2];
  const int t = threadIdx.x;
  if (t < CH2) {
    double cnt  = (double)NB * NP;
    double mean = stats2[t] / cnt;
    double var  = stats2[CH2 + t] / cnt - mean * mean;
    float scale = gamma2[t] / sqrtf((float)var + BN_EPS);
    s2s[t] = scale; s2h[t] = beta2[t] - (float)mean * scale;
  }
  const int qbase = blockIdx.x * 8;
  if (t < 48) {
    int qs = t / 6, c = t % 6;
    int qi = qbase + qs;
    float v = fmaf(sc1[c], p[qi*CH1 + c] - minq[qi*CH1 + c], sc1[CH1 + c]);
    me_lds[qs][c] = v > 0.f ? v : expm1f(v);
  }
  __syncthreads();
  const int qs = t >> 5, o = t & 31;
  const int qi = qbase + qs;
  float y = b2[o];
#pragma unroll
  for (int c = 0; c < CH1; ++c) y = fmaf(me_lds[qs][c], W2[c*CH2 + o], y);
  float r = fmaf(s2s[o], y, s2h[o]);
  out[(size_t)qi*CH2 + o] = r > 0.f ? r : expm1f(r);
}

extern "C" void kernel_launch(void* const* d_in, const int* in_sizes, int n_in,
                              void* d_out, int out_size, void* d_ws, size_t ws_size,
                              hipStream_t stream) {
  const float* x      = (const float*)d_in[0];
  const float* W1     = (const float*)d_in[1];
  const float* b1     = (const float*)d_in[2];
  const float* gamma1 = (const float*)d_in[3];
  const float* beta1  = (const float*)d_in[4];
  const float* W2     = (const float*)d_in[5];
  const float* b2     = (const float*)d_in[6];
  const float* gamma2 = (const float*)d_in[7];
  const float* beta2  = (const float*)d_in[8];
  float* out = (float*)d_out;
  char* ws = (char*)d_ws;

  double* s1rep  = (double*)(ws + OFF_S1REP);
  double* stats2 = (double*)(ws + OFF_STATS2);
  float* sc1  = (float*)(ws + OFF_SC1);
  float* p    = (float*)(ws + OFF_P);
  float* minq = (float*)(ws + OFF_MINQ);

  hipMemsetAsync(ws, 0, 1280, stream);  // zero BN stat accumulators

  knn_kernel   <<<dim3(NBLK),       dim3(512), 0, stream>>>(x, W1, b1, p, minq, s1rep);
  stage2_kernel<<<dim3(NB*NP/128),  dim3(128), 0, stream>>>(p, minq, s1rep, gamma1, beta1,
                                                            W2, b2, sc1, stats2);
  out_kernel   <<<dim3(NB*NP/8),    dim3(256), 0, stream>>>(p, minq, sc1, W2, b2,
                                                            stats2, gamma2, beta2, out);
}